// Round 15
// baseline (903.959 us; speedup 1.0000x reference)
//
#include <hip/hip_runtime.h>
#include <hip/hip_bf16.h>
#include <math.h>

#define BB 8
#define KK 19
#define PP 16384
#define CC 256
#define NN (BB*PP)           // 131072
#define KA_C 10.0f
#define IGNORE_L 255
#define CETHR 0.22314355131420976f   // -log(0.8)
#define AQ 524288                    // PP*32, one a-quarter [px][32]

// ws offsets (in floats)
#define OFF_FEATN   0                          // bf16[BB*CC*PP] (c-major)
#define OFF_FEATNT  16777216                   // bf16[BB*PP*CC] (px-major)
#define OFF_PROTO   33554432                   // 4864   [c][k]
#define OFF_COUNTS  (OFF_PROTO+4864)           // 32
#define OFF_SCAL    (OFF_COUNTS+32)            // 16
#define OFF_UINIT   (OFF_SCAL+16)              // 4864  [c][k]
#define OFF_U       (OFF_UINIT+4864)           // 4864  [k][c] f32
#define OFF_UBF     (OFF_U+4864)               // 4224  (= 32*264 bf16, padded)
#define OFF_A       (OFF_UBF+4224)             // 8 x AQ (2 sets x 4 quarters, [px][32])
#define OFF_UPART   (OFF_A+8*AQ)               // 16*4864 atomic accumulator
#define OFF_NORM    (OFF_UPART+77824)          // NN floats
#define OFF_LOGT    (OFF_NORM+131072)          // NN*20 floats
// end ≈ 41M floats = 164 MB

typedef __attribute__((ext_vector_type(8))) short short8v;
typedef __attribute__((ext_vector_type(4))) float f32x4;

static __device__ __forceinline__ float bflo(unsigned int v){
    union{unsigned int i; float f;} x; x.i = v << 16; return x.f;
}
static __device__ __forceinline__ unsigned short f2bf(float f){
    union{float f; unsigned int i;} x; x.f = f;
    unsigned int r = (x.i + 0x7fffu + ((x.i >> 16) & 1u)) >> 16;
    return (unsigned short)r;
}
static __device__ __forceinline__ float rowsum16(float v){
    v += __shfl_xor(v,1); v += __shfl_xor(v,2);
    v += __shfl_xor(v,4); v += __shfl_xor(v,8);
    return v;
}
static __device__ __forceinline__ float rowmax16(float v){
    v = fmaxf(v, __shfl_xor(v,1)); v = fmaxf(v, __shfl_xor(v,2));
    v = fmaxf(v, __shfl_xor(v,4)); v = fmaxf(v, __shfl_xor(v,8));
    return v;
}

// ---------------- counts ----------------
__global__ __launch_bounds__(256) void counts_kernel(const int* __restrict__ target,
                                                     float* __restrict__ ws) {
    __shared__ int cnt[KK];
    if (threadIdx.x < KK) cnt[threadIdx.x]=0;
    __syncthreads();
    for (int i = blockIdx.x*256 + threadIdx.x; i < NN; i += gridDim.x*256) {
        int t = target[i];
        if (t >= 0 && t < KK) atomicAdd(&cnt[t], 1);
    }
    __syncthreads();
    if (threadIdx.x < KK) atomicAdd(&ws[OFF_COUNTS + threadIdx.x], (float)cnt[threadIdx.x]);
}

// ---------------- ssct: reg-cached norm + bf16 featn (paired stores) + transpose ----------------
__global__ __launch_bounds__(256) void ssct_kernel(const float* __restrict__ feat,
                                                   unsigned short* __restrict__ featn,
                                                   unsigned short* __restrict__ featn_T,
                                                   float* __restrict__ normf) {
    __shared__ float part[4][64];
    __shared__ float rn_lds[64];
    __shared__ unsigned short tTus[64][270];   // row stride 540B -> bank step 7 (coprime 32)
    int blk = blockIdx.x;          // 2048: b = blk>>8, 64-px chunk
    int b = blk >> 8;
    int px0 = (blk & 255) * 64;
    int tid = threadIdx.x;
    int l = tid & 63, w = tid >> 6;   // lane owns px = px0+l, wave owns c-slice w*64..
    const float* fb = feat + (size_t)b*CC*PP;
    int c0 = w*64;
    float fv[64];
    float ss = 0.f;
#pragma unroll
    for (int cc=0; cc<64; cc++) {
        fv[cc] = fb[(size_t)(c0+cc)*PP + px0 + l];
        ss = fmaf(fv[cc], fv[cc], ss);
    }
    part[w][l] = ss;
    __syncthreads();
    if (tid < 64) {
        float s = part[0][tid]+part[1][tid]+part[2][tid]+part[3][tid];
        float nrm = fmaxf(sqrtf(s), 1e-12f);
        normf[(size_t)b*PP + px0 + tid] = nrm;
        rn_lds[tid] = 1.0f/nrm;
    }
    __syncthreads();
    float r = rn_lds[l];
    unsigned short* ob = featn + (size_t)b*CC*PP + px0;
#pragma unroll
    for (int cc=0; cc<64; cc++) {
        int c = c0 + cc;
        unsigned int us = f2bf(fv[cc] * r);
        tTus[l][c] = (unsigned short)us;
        unsigned int partner = __shfl_xor(us, 1);
        if ((l & 1) == 0) {
            unsigned int v = us | (partner<<16);
            *(unsigned int*)&ob[(size_t)c*PP + l] = v;
        }
    }
    __syncthreads();
    unsigned short* obT = featn_T + ((size_t)b*PP + px0)*CC;
    for (int j=0; j<32; j++) {
        int flat = j*256 + tid;        // 8192 uints = 64px * 128
        int px = flat >> 7, cu = flat & 127;
        unsigned int v = *(const unsigned int*)&tTus[px][cu*2];
        *(unsigned int*)&obT[(size_t)px*CC + cu*2] = v;
    }
}

// ---------------- logit transpose: [b][k][px] -> [b][px][20] ----------------
__global__ __launch_bounds__(256) void logt_kernel(const float* __restrict__ logit,
                                                   float* __restrict__ logt) {
    __shared__ float t[256][21];
    int blk = blockIdx.x;      // 512 = 8 b * 64 chunks of 256 px
    int b = blk >> 6;
    int px0 = (blk & 63) * 256;
    int tid = threadIdx.x;
    for (int k=0;k<KK;k++)
        t[tid][k] = logit[((size_t)b*KK + k)*PP + px0 + tid];
    __syncthreads();
    float* dst = logt + ((size_t)b*PP + px0)*20;
    for (int j=0; j<20; j++) {
        int flat = j*256 + tid;         // 5120 = 256 px * 20
        int px = flat / 20, k = flat % 20;
        dst[flat] = (k<KK) ? t[px][k] : 0.f;
    }
}

// ---------------- proto via MFMA -> atomic 16-slot accumulator ----------------
__global__ __launch_bounds__(256) void proto_mfma_kernel(const unsigned short* __restrict__ featn,
                                                         const int* __restrict__ target,
                                                         const float* __restrict__ normf,
                                                         float* __restrict__ up16) {
    __shared__ int tgt_lds[4][64];
    __shared__ unsigned short nrm_lds[4][64];
    int tid = threadIdx.x;
    int blk = blockIdx.x;
    int pxtile = blk & 255;
    int bgrp = blk >> 8;
    {
        int bi = tid >> 6, j = tid & 63;
        int bb = bgrp*4 + bi;
        tgt_lds[bi][j] = target[(size_t)bb*PP + pxtile*64 + j];
        nrm_lds[bi][j] = f2bf(normf[(size_t)bb*PP + pxtile*64 + j]);
    }
    __syncthreads();
    int lane = tid & 63, wid = tid >> 6;
    int g = lane >> 4, lc = lane & 15;

    f32x4 upacc[4][2];
#pragma unroll
    for (int m=0;m<4;m++)
#pragma unroll
        for (int n=0;n<2;n++) upacc[m][n] = (f32x4){0.f,0.f,0.f,0.f};

    for (int bi=0; bi<4; bi++) {
        int bb = bgrp*4 + bi;
        union { unsigned int u[4]; short8v s; } bfr[2][2];
#pragma unroll
        for (int ks=0; ks<2; ks++) {
            int pxo = ks*32 + g*8;
#pragma unroll
            for (int j2=0;j2<4;j2++) {
                int p0i = pxo + 2*j2, p1i = pxo + 2*j2 + 1;
                int t0 = tgt_lds[bi][p0i], t1 = tgt_lds[bi][p1i];
                unsigned int n0 = nrm_lds[bi][p0i], n1 = nrm_lds[bi][p1i];
                int kk1 = lc + 16;
                bfr[ks][0].u[j2] = (t0==lc ? n0:0u) | ((t1==lc ? n1:0u)<<16);
                bfr[ks][1].u[j2] = (t0==kk1? n0:0u) | ((t1==kk1? n1:0u)<<16);
            }
        }
#pragma unroll
        for (int m=0;m<4;m++) {
            int c = wid*64 + m*16 + lc;
            const unsigned short* fr = featn + ((size_t)bb*CC + c)*PP + pxtile*64;
#pragma unroll
            for (int ks=0; ks<2; ks++) {
                int pxo = ks*32 + g*8;
                union { uint4 u4; short8v s; } af2;
                af2.u4 = *(const uint4*)&fr[pxo];
                upacc[m][0] = __builtin_amdgcn_mfma_f32_16x16x32_bf16(af2.s, bfr[ks][0].s, upacc[m][0], 0,0,0);
                upacc[m][1] = __builtin_amdgcn_mfma_f32_16x16x32_bf16(af2.s, bfr[ks][1].s, upacc[m][1], 0,0,0);
            }
        }
    }
    float* slot = up16 + (size_t)(blk & 15)*4864;
#pragma unroll
    for (int m=0;m<4;m++) {
        int cb = wid*64 + m*16 + g*4;
#pragma unroll
        for (int n=0;n<2;n++) {
            int kk = lc + 16*n;
            if (kk < KK) {
#pragma unroll
                for (int r=0;r<4;r++)
                    atomicAdd(&slot[(size_t)(cb+r)*KK + kk], upacc[m][n][r]);
            }
        }
    }
}

// ---------------- protored: 16-slot sum -> proto, then zero slots ----------------
__global__ __launch_bounds__(256) void protored_kernel(float* __restrict__ up16,
                                                       float* __restrict__ ws) {
    int e = blockIdx.x*256 + threadIdx.x;   // 19*256 = 4864
    float s = 0.f;
#pragma unroll
    for (int i=0;i<16;i++) s += up16[(size_t)i*4864 + e];
    ws[OFF_PROTO + e] = s;
#pragma unroll
    for (int i=0;i<16;i++) up16[(size_t)i*4864 + e] = 0.f;
}

// ---------------- setup: u_init, u0, contrast ----------------
__global__ __launch_bounds__(256) void setup_kernel(const float* __restrict__ pd,
                                                    float* __restrict__ ws) {
    int c = threadIdx.x;
    __shared__ float red[256];
    __shared__ float nrm[KK];
    __shared__ float lds_ui[256][KK];
    float cnts[KK], vi[KK];
#pragma unroll
    for (int k=0;k<KK;k++) cnts[k] = ws[OFF_COUNTS+k];
#pragma unroll
    for (int k=0;k<KK;k++) vi[k] = ws[OFF_PROTO + c*KK + k] / (cnts[k] + 1e-6f);
    for (int k=0;k<KK;k++) {
        red[c] = vi[k]*vi[k];
        __syncthreads();
        for (int s=128;s>0;s>>=1){ if (c<s) red[c]+=red[c+s]; __syncthreads(); }
        if (c==0) nrm[k] = fmaxf(sqrtf(red[0]), 1e-12f);
        __syncthreads();
    }
#pragma unroll
    for (int k=0;k<KK;k++) { vi[k] = vi[k]/nrm[k]; lds_ui[c][k] = vi[k]; ws[OFF_UINIT + c*KK + k] = vi[k]; }
    __syncthreads();
    float w0[KK];
#pragma unroll
    for (int k=0;k<KK;k++) w0[k] = (cnts[k]==0.f) ? pd[c*KK+k] : vi[k];
    for (int k=0;k<KK;k++) {
        red[c] = w0[k]*w0[k];
        __syncthreads();
        for (int s=128;s>0;s>>=1){ if (c<s) red[c]+=red[c+s]; __syncthreads(); }
        if (c==0) nrm[k] = fmaxf(sqrtf(red[0]), 1e-12f);
        __syncthreads();
    }
    unsigned short* ubf = (unsigned short*)(ws + OFF_UBF);
#pragma unroll
    for (int k=0;k<KK;k++) {
        float uv = w0[k] / nrm[k];
        ws[OFF_U + k*CC + c] = uv;
        ubf[k*264 + c] = f2bf(uv);
    }
    float m[KK]; float Kn=0.f;
#pragma unroll
    for (int k=0;k<KK;k++){ m[k] = (cnts[k]==0.f)?0.f:1.f; Kn += m[k]; }
    float csum = 0.f;
    for (int idx = c; idx < KK*KK; idx += 256) {
        int k1 = idx / KK, k2 = idx % KK;
        if (m[k1]!=0.f && m[k2]!=0.f) {
            float gg=0.f;
            for (int cc2=0; cc2<CC; cc2++) gg += lds_ui[cc2][k1]*lds_ui[cc2][k2];
            csum += gg;
        }
    }
    red[c]=csum; __syncthreads();
    for (int s=128;s>0;s>>=1){ if (c<s) red[c]+=red[c+s]; __syncthreads(); }
    if (c==0) ws[OFF_SCAL+4] = (red[0] - Kn) / (Kn * (Kn - 1.f));
}

// ---------------- PU via MFMA: atomic 16-slot u-accumulation ----------------
__global__ __launch_bounds__(256) void pu_kernel(const unsigned short* __restrict__ featn,
                                                 const unsigned short* __restrict__ featn_T,
                                                 const unsigned short* __restrict__ ubf,
                                                 const float* __restrict__ aRbase,
                                                 float* __restrict__ aWbase,
                                                 float* __restrict__ up16,
                                                 int uniform_a) {
    __shared__ __attribute__((aligned(16))) unsigned short u_lds[32*264];
    __shared__ __attribute__((aligned(16))) unsigned short p_lds[32*72];
    int tid = threadIdx.x;
    {
        const uint4* src = (const uint4*)ubf;
        uint4* dst = (uint4*)u_lds;
        for (int i=tid; i<1056; i+=256) dst[i] = src[i];
    }
    __syncthreads();
    int blk = blockIdx.x;
    int pxtile = blk & 255;
    int bgrp = blk >> 8;          // 0..3
    int lane = tid & 63, wid = tid >> 6;
    int g = lane >> 4, lc = lane & 15;
    int px_w = pxtile*64 + wid*16;

    float a0r[4], a1r[4];
    if (uniform_a) {
#pragma unroll
        for (int r=0;r<4;r++){ a0r[r]=1.0f/(float)KK; a1r[r]=1.0f/(float)KK; }
    } else {
        int k1 = (lc+16 > KK-1) ? (KK-1) : (lc+16);
#pragma unroll
        for (int r=0;r<4;r++) {
            int pxg = px_w + g*4 + r;
            float s0 = aRbase[0*AQ + (size_t)pxg*32 + lc] + aRbase[1*AQ + (size_t)pxg*32 + lc]
                     + aRbase[2*AQ + (size_t)pxg*32 + lc] + aRbase[3*AQ + (size_t)pxg*32 + lc];
            float s1 = aRbase[0*AQ + (size_t)pxg*32 + k1] + aRbase[1*AQ + (size_t)pxg*32 + k1]
                     + aRbase[2*AQ + (size_t)pxg*32 + k1] + aRbase[3*AQ + (size_t)pxg*32 + k1];
            a0r[r] = s0*0.125f;
            a1r[r] = s1*0.125f;
        }
    }

    f32x4 upacc[4][2];
#pragma unroll
    for (int m=0;m<4;m++)
#pragma unroll
        for (int n=0;n<2;n++) upacc[m][n] = (f32x4){0.f,0.f,0.f,0.f};
    float aacc[2][4];
#pragma unroll
    for (int n=0;n<2;n++)
#pragma unroll
        for (int r=0;r<4;r++) aacc[n][r]=0.f;

    for (int bi=0; bi<2; bi++) {
        int bb = bgrp*2 + bi;
        const unsigned short* fb = featn + (size_t)bb*CC*PP;
        const unsigned short* fTrow = featn_T + ((size_t)bb*PP + px_w + lc)*CC;
        f32x4 acc0 = (f32x4){0.f,0.f,0.f,0.f};
        f32x4 acc1 = (f32x4){0.f,0.f,0.f,0.f};
#pragma unroll
        for (int ks=0; ks<8; ks++) {
            int cbase = ks*32 + g*8;
            union { uint4 u4; short8v s; } af, bf0, bf1;
            af.u4  = *(const uint4*)&fTrow[cbase];
            bf0.u4 = *(const uint4*)&u_lds[(size_t)lc*264 + cbase];
            bf1.u4 = *(const uint4*)&u_lds[(size_t)(lc+16)*264 + cbase];
            acc0 = __builtin_amdgcn_mfma_f32_16x16x32_bf16(af.s, bf0.s, acc0, 0,0,0);
            acc1 = __builtin_amdgcn_mfma_f32_16x16x32_bf16(af.s, bf1.s, acc1, 0,0,0);
        }
#pragma unroll
        for (int r=0;r<4;r++) {
            float e0 = a0r[r] * __expf(KA_C * acc0[r]);
            float e1 = (lc+16 < KK) ? a1r[r] * __expf(KA_C * acc1[r]) : 0.f;
            float sv = rowsum16(e0 + e1);
            float inv = 1.0f/sv;
            float p0 = e0*inv, p1 = e1*inv;
            aacc[0][r] += p0; aacc[1][r] += p1;
            int pl = wid*16 + g*4 + r;
            p_lds[(size_t)lc*72 + pl]      = f2bf(p0);
            p_lds[(size_t)(lc+16)*72 + pl] = f2bf(p1);
        }
        __syncthreads();
#pragma unroll
        for (int m=0;m<4;m++) {
            int c = wid*64 + m*16 + lc;
            const unsigned short* fr = fb + (size_t)c*PP + pxtile*64;
#pragma unroll
            for (int ks=0; ks<2; ks++) {
                int pxo = ks*32 + g*8;
                union { uint4 u4; short8v s; } af2, bp0, bp1;
                af2.u4 = *(const uint4*)&fr[pxo];
                bp0.u4 = *(const uint4*)&p_lds[(size_t)lc*72 + pxo];
                bp1.u4 = *(const uint4*)&p_lds[(size_t)(lc+16)*72 + pxo];
                upacc[m][0] = __builtin_amdgcn_mfma_f32_16x16x32_bf16(af2.s, bp0.s, upacc[m][0], 0,0,0);
                upacc[m][1] = __builtin_amdgcn_mfma_f32_16x16x32_bf16(af2.s, bp1.s, upacc[m][1], 0,0,0);
            }
        }
        __syncthreads();
    }
    float* slot = up16 + (size_t)(blk & 15)*4864;
#pragma unroll
    for (int m=0;m<4;m++) {
        int cb = wid*64 + m*16 + g*4;
#pragma unroll
        for (int n=0;n<2;n++) {
            int kk = lc + 16*n;
            if (kk < KK) {
#pragma unroll
                for (int r=0;r<4;r++)
                    atomicAdd(&slot[(size_t)(cb+r)*KK + kk], upacc[m][n][r]);
            }
        }
    }
    float* aOut = aWbase + (size_t)bgrp*AQ;
#pragma unroll
    for (int n=0;n<2;n++) {
        int kk = lc + 16*n;
        if (kk < KK) {
#pragma unroll
            for (int r=0;r<4;r++) {
                int pxg = px_w + g*4 + r;
                aOut[(size_t)pxg*32 + kk] = aacc[n][r];
            }
        }
    }
}

// ---------------- R2: 16-slot sum + normalize -> u, then zero slots ----------------
__global__ __launch_bounds__(256) void r2_kernel(float* __restrict__ up16,
                                                 float* __restrict__ ws) {
    int k = blockIdx.x;   // 0..18
    int c = threadIdx.x;  // 0..255
    float s = 0.f;
#pragma unroll
    for (int i=0;i<16;i++) s += up16[(size_t)i*4864 + c*KK + k];
    __shared__ float red[256];
    red[c] = s*s; __syncthreads();
    for (int q=128;q>0;q>>=1){ if (c<q) red[c]+=red[c+q]; __syncthreads(); }
    float nrm = fmaxf(sqrtf(red[0]), 1e-12f);
    float uv = s / nrm;
    ws[OFF_U + k*CC + c] = uv;
    ((unsigned short*)(ws + OFF_UBF))[k*264 + c] = f2bf(uv);
#pragma unroll
    for (int i=0;i<16;i++) up16[(size_t)i*4864 + c*KK + k] = 0.f;
}

// ---------------- final via MFMA (coalesced logit_T + line-local a) ----------------
__global__ __launch_bounds__(256) void final_mfma_kernel(const unsigned short* __restrict__ featn_T,
                                                         const float* __restrict__ logt,
                                                         const int* __restrict__ target,
                                                         const unsigned short* __restrict__ ubf,
                                                         const float* __restrict__ aFbase,
                                                         float* __restrict__ scal) {
    __shared__ __attribute__((aligned(16))) unsigned short u_lds[32*264];
    int tid = threadIdx.x;
    {
        const uint4* src = (const uint4*)ubf;
        uint4* dst = (uint4*)u_lds;
        for (int i=tid; i<1056; i+=256) dst[i] = src[i];
    }
    __syncthreads();
    int blk = blockIdx.x;      // 512 = 2 bgrps x 256 pxtiles
    int pxtile = blk & 255;
    int bgrp = blk >> 8;
    int lane = tid & 63, wid = tid >> 6;
    int g = lane >> 4, lc = lane & 15;
    int px_w = pxtile*64 + wid*16;
    bool valid1 = (lc+16) < KK;

    float v_vmf=0.f, v_cons=0.f, v_ce=0.f, v_cnt=0.f;

    for (int bi=0; bi<4; bi++) {
        int bb = bgrp*4 + bi;
        const unsigned short* fTrow = featn_T + ((size_t)bb*PP + px_w + lc)*CC;
        f32x4 acc0 = (f32x4){0.f,0.f,0.f,0.f};
        f32x4 acc1 = (f32x4){0.f,0.f,0.f,0.f};
#pragma unroll
        for (int ks=0; ks<8; ks++) {
            int cbase = ks*32 + g*8;
            union { uint4 u4; short8v s; } af, bf0, bf1;
            af.u4  = *(const uint4*)&fTrow[cbase];
            bf0.u4 = *(const uint4*)&u_lds[(size_t)lc*264 + cbase];
            bf1.u4 = *(const uint4*)&u_lds[(size_t)(lc+16)*264 + cbase];
            acc0 = __builtin_amdgcn_mfma_f32_16x16x32_bf16(af.s, bf0.s, acc0, 0,0,0);
            acc1 = __builtin_amdgcn_mfma_f32_16x16x32_bf16(af.s, bf1.s, acc1, 0,0,0);
        }
#pragma unroll
        for (int r=0;r<4;r++) {
            int pxg = px_w + g*4 + r;
            float d0 = acc0[r], d1 = acc1[r];
            float av0 = (aFbase[0*AQ + (size_t)pxg*32 + lc] + aFbase[1*AQ + (size_t)pxg*32 + lc]
                       + aFbase[2*AQ + (size_t)pxg*32 + lc] + aFbase[3*AQ + (size_t)pxg*32 + lc])*0.125f;
            float av1 = 0.f;
            if (valid1) {
                int k1 = lc+16;
                av1 = (aFbase[0*AQ + (size_t)pxg*32 + k1] + aFbase[1*AQ + (size_t)pxg*32 + k1]
                     + aFbase[2*AQ + (size_t)pxg*32 + k1] + aFbase[3*AQ + (size_t)pxg*32 + k1])*0.125f;
            }
            float e0 = av0 * __expf(KA_C * d0);
            float e1 = valid1 ? av1 * __expf(KA_C * d1) : 0.f;
            float den = rowsum16(e0 + e1);
            float inv = 1.0f/den;
            float p0 = e0*inv, p1 = e1*inv;
            float vt = -p0*(__logf(av0+1e-6f) + KA_C*d0);
            if (valid1) vt += -p1*(__logf(av1+1e-6f) + KA_C*d1);
            float vt_row = rowsum16(vt);
            const float* lrow = logt + ((size_t)bb*PP + pxg)*20;
            float lg0 = lrow[lc];
            float lg1 = valid1 ? lrow[lc+16] : -3.4e38f;
            float mx = rowmax16(fmaxf(lg0, lg1));
            float sme = __expf(lg0-mx) + (valid1 ? __expf(lg1-mx) : 0.f);
            sme = rowsum16(sme);
            float lse = mx + __logf(sme);
            float ct = -p0*(lg0-lse);
            if (valid1) ct += -p1*(lg1-lse);
            float ct_row = rowsum16(ct);
            int t = target[(size_t)bb*PP + pxg];
            float ltt = (lc==t ? lg0 : 0.f) + ((valid1 && lc+16==t) ? lg1 : 0.f);
            float lt = rowsum16(ltt);
            if (lc==0) {
                v_vmf += vt_row;
                v_cons += ct_row;
                if (t != IGNORE_L) { v_ce += fmaxf(lse - lt, CETHR); v_cnt += 1.f; }
            }
        }
    }
    __shared__ float red[4][4];
    int w = tid >> 6;
    float v0=v_vmf, v1=v_cons, v2=v_ce, v3=v_cnt;
#pragma unroll
    for (int s=32;s>0;s>>=1) {
        v0 += __shfl_xor(v0, s); v1 += __shfl_xor(v1, s);
        v2 += __shfl_xor(v2, s); v3 += __shfl_xor(v3, s);
    }
    if ((tid&63)==0){ red[w][0]=v0; red[w][1]=v1; red[w][2]=v2; red[w][3]=v3; }
    __syncthreads();
    if (tid==0) {
        atomicAdd(&scal[0], red[0][0]+red[1][0]+red[2][0]+red[3][0]);
        atomicAdd(&scal[1], red[0][1]+red[1][1]+red[2][1]+red[3][1]);
        atomicAdd(&scal[2], red[0][2]+red[1][2]+red[2][2]+red[3][2]);
        atomicAdd(&scal[3], red[0][3]+red[1][3]+red[2][3]+red[3][3]);
    }
}

// ---------------- finalize ----------------
__global__ __launch_bounds__(256) void finalize_kernel(const float* __restrict__ ws,
                                                       float* __restrict__ out) {
    if (blockIdx.x==0 && threadIdx.x==0) {
        float cnt_all = (float)BB*(float)PP*(float)KK;
        float vmf  = ws[OFF_SCAL+0] / cnt_all / logf((float)KK);
        float cons = ws[OFF_SCAL+1] / cnt_all;
        float ce   = ws[OFF_SCAL+2] / (ws[OFF_SCAL+3] + 1e-6f);
        float contrast = ws[OFF_SCAL+4];
        out[0] = ce + vmf + contrast + cons;
    }
    int i = blockIdx.x*256 + threadIdx.x;
    if (i < 4864) out[1+i] = ws[OFF_PROTO+i];
    if (blockIdx.x==0 && threadIdx.x < KK) out[1+4864+threadIdx.x] = ws[OFF_COUNTS+threadIdx.x];
}

extern "C" void kernel_launch(void* const* d_in, const int* in_sizes, int n_in,
                              void* d_out, int out_size, void* d_ws, size_t ws_size,
                              hipStream_t stream) {
    (void)in_sizes; (void)n_in; (void)out_size; (void)ws_size;
    const float* logit  = (const float*)d_in[0];
    const int*   target = (const int*)d_in[1];
    const float* feat   = (const float*)d_in[2];
    const float* pd     = (const float*)d_in[4];
    float* out = (float*)d_out;
    float* ws  = (float*)d_ws;

    unsigned short* featn   = (unsigned short*)ws;
    unsigned short* featn_T = (unsigned short*)(ws + OFF_FEATNT);
    unsigned short* ubf     = (unsigned short*)(ws + OFF_UBF);
    float* up16  = ws + OFF_UPART;
    float* normf = ws + OFF_NORM;
    float* logt  = ws + OFF_LOGT;
    float* scal  = ws + OFF_SCAL;
    float* aSet[2] = { ws + OFF_A, ws + OFF_A + (size_t)4*AQ };

    hipMemsetAsync(ws + OFF_PROTO, 0, 4912*sizeof(float), stream);
    hipMemsetAsync(ws + OFF_UBF, 0, 4224*sizeof(float), stream);
    hipMemsetAsync(up16, 0, 16*4864*sizeof(float), stream);
    ssct_kernel<<<2048, 256, 0, stream>>>(feat, featn, featn_T, normf);
    counts_kernel<<<256, 256, 0, stream>>>(target, ws);
    logt_kernel<<<512, 256, 0, stream>>>(logit, logt);
    proto_mfma_kernel<<<512, 256, 0, stream>>>(featn, target, normf, up16);
    protored_kernel<<<19, 256, 0, stream>>>(up16, ws);
    setup_kernel<<<1, 256, 0, stream>>>(pd, ws);

    for (int t=0; t<10; t++) {
        if (t > 0)
            r2_kernel<<<KK, 256, 0, stream>>>(up16, ws);
        pu_kernel<<<1024, 256, 0, stream>>>(featn, featn_T, ubf,
                                            aSet[t&1], aSet[(t+1)&1],
                                            up16, (t==0)?1:0);
    }
    r2_kernel<<<KK, 256, 0, stream>>>(up16, ws);
    final_mfma_kernel<<<512, 256, 0, stream>>>(featn_T, logt, target, ubf, aSet[0], scal);
    finalize_kernel<<<20, 256, 0, stream>>>(ws, out);
}

// Round 16
// 555.885 us; speedup vs baseline: 1.6262x; 1.6262x over previous
//
#include <hip/hip_runtime.h>
#include <hip/hip_bf16.h>
#include <math.h>

#define BB 8
#define KK 19
#define PP 16384
#define CC 256
#define NN (BB*PP)           // 131072
#define KA_C 10.0f
#define IGNORE_L 255
#define CETHR 0.22314355131420976f   // -log(0.8)
#define AQ 524288                    // PP*32, one a-half [px][32]

// ws offsets (in floats)
#define OFF_FEATN   0                          // bf16[BB*CC*PP] (c-major)
#define OFF_FEATNT  16777216                   // bf16[BB*PP*CC] (px-major)
#define OFF_PROTO   33554432                   // 4864   [c][k]
#define OFF_COUNTS  (OFF_PROTO+4864)           // 32
#define OFF_SCAL    (OFF_COUNTS+32)            // 16
#define OFF_UINIT   (OFF_SCAL+16)              // 4864  [c][k]
#define OFF_U       (OFF_UINIT+4864)           // 4864  [k][c] f32
#define OFF_UBF     (OFF_U+4864)               // 4224  (= 32*264 bf16, padded)
#define OFF_A       (OFF_UBF+4224)             // 4 x AQ (2 sets x 2 halves, [px][32])
#define OFF_UPART   (OFF_A+4*AQ)               // 512*4864
#define OFF_R1      (OFF_UPART+2490368)        // 16*4864
#define OFF_NORM    (OFF_R1+77824)             // NN floats
#define OFF_LOGT    (OFF_NORM+131072)          // NN*20 floats
// end ≈ 42M floats = 168 MB

typedef __attribute__((ext_vector_type(8))) short short8v;
typedef __attribute__((ext_vector_type(4))) float f32x4;

static __device__ __forceinline__ float bflo(unsigned int v){
    union{unsigned int i; float f;} x; x.i = v << 16; return x.f;
}
static __device__ __forceinline__ unsigned short f2bf(float f){
    union{float f; unsigned int i;} x; x.f = f;
    unsigned int r = (x.i + 0x7fffu + ((x.i >> 16) & 1u)) >> 16;
    return (unsigned short)r;
}
static __device__ __forceinline__ float rowsum16(float v){
    v += __shfl_xor(v,1); v += __shfl_xor(v,2);
    v += __shfl_xor(v,4); v += __shfl_xor(v,8);
    return v;
}
static __device__ __forceinline__ float rowmax16(float v){
    v = fmaxf(v, __shfl_xor(v,1)); v = fmaxf(v, __shfl_xor(v,2));
    v = fmaxf(v, __shfl_xor(v,4)); v = fmaxf(v, __shfl_xor(v,8));
    return v;
}

// ---------------- counts ----------------
__global__ __launch_bounds__(256) void counts_kernel(const int* __restrict__ target,
                                                     float* __restrict__ ws) {
    __shared__ int cnt[KK];
    if (threadIdx.x < KK) cnt[threadIdx.x]=0;
    __syncthreads();
    for (int i = blockIdx.x*256 + threadIdx.x; i < NN; i += gridDim.x*256) {
        int t = target[i];
        if (t >= 0 && t < KK) atomicAdd(&cnt[t], 1);
    }
    __syncthreads();
    if (threadIdx.x < KK) atomicAdd(&ws[OFF_COUNTS + threadIdx.x], (float)cnt[threadIdx.x]);
}

// ---------------- ssct: reg-cached norm + bf16 featn + fused transpose ----------------
__global__ __launch_bounds__(256) void ssct_kernel(const float* __restrict__ feat,
                                                   unsigned short* __restrict__ featn,
                                                   unsigned short* __restrict__ featn_T,
                                                   float* __restrict__ normf) {
    __shared__ float part[4][64];
    __shared__ float rn_lds[64];
    __shared__ unsigned short tTus[64][270];   // row stride 540B -> bank step 7 (coprime 32)
    int blk = blockIdx.x;          // 2048: b = blk>>8, 64-px chunk
    int b = blk >> 8;
    int px0 = (blk & 255) * 64;
    int tid = threadIdx.x;
    int l = tid & 63, w = tid >> 6;   // lane owns px = px0+l, wave owns c-slice w*64..
    const float* fb = feat + (size_t)b*CC*PP;
    int c0 = w*64;
    float fv[64];
    float ss = 0.f;
#pragma unroll
    for (int cc=0; cc<64; cc++) {
        fv[cc] = fb[(size_t)(c0+cc)*PP + px0 + l];
        ss = fmaf(fv[cc], fv[cc], ss);
    }
    part[w][l] = ss;
    __syncthreads();
    if (tid < 64) {
        float s = part[0][tid]+part[1][tid]+part[2][tid]+part[3][tid];
        float nrm = fmaxf(sqrtf(s), 1e-12f);
        normf[(size_t)b*PP + px0 + tid] = nrm;
        rn_lds[tid] = 1.0f/nrm;
    }
    __syncthreads();
    float r = rn_lds[l];
    unsigned short* ob  = featn + (size_t)b*CC*PP + px0;
#pragma unroll
    for (int cc=0; cc<64; cc++) {
        int c = c0 + cc;
        unsigned short us = f2bf(fv[cc] * r);
        ob[(size_t)c*PP + l] = us;
        tTus[l][c] = us;
    }
    __syncthreads();
    unsigned short* obT = featn_T + ((size_t)b*PP + px0)*CC;
    for (int j=0; j<32; j++) {
        int flat = j*256 + tid;        // 8192 uints = 64px * 128
        int px = flat >> 7, cu = flat & 127;
        unsigned int v = *(const unsigned int*)&tTus[px][cu*2];
        *(unsigned int*)&obT[(size_t)px*CC + cu*2] = v;
    }
}

// ---------------- logit transpose: [b][k][px] -> [b][px][20] ----------------
__global__ __launch_bounds__(256) void logt_kernel(const float* __restrict__ logit,
                                                   float* __restrict__ logt) {
    __shared__ float t[256][21];
    int blk = blockIdx.x;      // 512 = 8 b * 64 chunks of 256 px
    int b = blk >> 6;
    int px0 = (blk & 63) * 256;
    int tid = threadIdx.x;
    for (int k=0;k<KK;k++)
        t[tid][k] = logit[((size_t)b*KK + k)*PP + px0 + tid];
    __syncthreads();
    float* dst = logt + ((size_t)b*PP + px0)*20;
    for (int j=0; j<20; j++) {
        int flat = j*256 + tid;         // 5120 = 256 px * 20
        int px = flat / 20, k = flat % 20;
        dst[flat] = (k<KK) ? t[px][k] : 0.f;
    }
}

// ---------------- proto via MFMA (512 blocks, 4-b groups) ----------------
__global__ __launch_bounds__(256) void proto_mfma_kernel(const unsigned short* __restrict__ featn,
                                                         const int* __restrict__ target,
                                                         const float* __restrict__ normf,
                                                         float* __restrict__ upart) {
    __shared__ int tgt_lds[4][64];
    __shared__ unsigned short nrm_lds[4][64];
    int tid = threadIdx.x;
    int blk = blockIdx.x;
    int pxtile = blk & 255;
    int bgrp = blk >> 8;
    {
        int bi = tid >> 6, j = tid & 63;
        int bb = bgrp*4 + bi;
        tgt_lds[bi][j] = target[(size_t)bb*PP + pxtile*64 + j];
        nrm_lds[bi][j] = f2bf(normf[(size_t)bb*PP + pxtile*64 + j]);
    }
    __syncthreads();
    int lane = tid & 63, wid = tid >> 6;
    int g = lane >> 4, lc = lane & 15;

    f32x4 upacc[4][2];
#pragma unroll
    for (int m=0;m<4;m++)
#pragma unroll
        for (int n=0;n<2;n++) upacc[m][n] = (f32x4){0.f,0.f,0.f,0.f};

    for (int bi=0; bi<4; bi++) {
        int bb = bgrp*4 + bi;
        union { unsigned int u[4]; short8v s; } bfr[2][2];
#pragma unroll
        for (int ks=0; ks<2; ks++) {
            int pxo = ks*32 + g*8;
#pragma unroll
            for (int j2=0;j2<4;j2++) {
                int p0i = pxo + 2*j2, p1i = pxo + 2*j2 + 1;
                int t0 = tgt_lds[bi][p0i], t1 = tgt_lds[bi][p1i];
                unsigned int n0 = nrm_lds[bi][p0i], n1 = nrm_lds[bi][p1i];
                int kk1 = lc + 16;
                bfr[ks][0].u[j2] = (t0==lc ? n0:0u) | ((t1==lc ? n1:0u)<<16);
                bfr[ks][1].u[j2] = (t0==kk1? n0:0u) | ((t1==kk1? n1:0u)<<16);
            }
        }
#pragma unroll
        for (int m=0;m<4;m++) {
            int c = wid*64 + m*16 + lc;
            const unsigned short* fr = featn + ((size_t)bb*CC + c)*PP + pxtile*64;
#pragma unroll
            for (int ks=0; ks<2; ks++) {
                int pxo = ks*32 + g*8;
                union { uint4 u4; short8v s; } af2;
                af2.u4 = *(const uint4*)&fr[pxo];
                upacc[m][0] = __builtin_amdgcn_mfma_f32_16x16x32_bf16(af2.s, bfr[ks][0].s, upacc[m][0], 0,0,0);
                upacc[m][1] = __builtin_amdgcn_mfma_f32_16x16x32_bf16(af2.s, bfr[ks][1].s, upacc[m][1], 0,0,0);
            }
        }
    }
#pragma unroll
    for (int m=0;m<4;m++) {
        int cb = wid*64 + m*16 + g*4;
#pragma unroll
        for (int n=0;n<2;n++) {
            int kk = lc + 16*n;
            if (kk < KK) {
#pragma unroll
                for (int r=0;r<4;r++)
                    upart[(size_t)blk*4864 + (size_t)(cb+r)*KK + kk] = upacc[m][n][r];
            }
        }
    }
}

// ---------------- setup: u_init, u0, contrast ----------------
__global__ __launch_bounds__(256) void setup_kernel(const float* __restrict__ pd,
                                                    float* __restrict__ ws) {
    int c = threadIdx.x;
    __shared__ float red[256];
    __shared__ float nrm[KK];
    __shared__ float lds_ui[256][KK];
    float cnts[KK], vi[KK];
#pragma unroll
    for (int k=0;k<KK;k++) cnts[k] = ws[OFF_COUNTS+k];
#pragma unroll
    for (int k=0;k<KK;k++) vi[k] = ws[OFF_PROTO + c*KK + k] / (cnts[k] + 1e-6f);
    for (int k=0;k<KK;k++) {
        red[c] = vi[k]*vi[k];
        __syncthreads();
        for (int s=128;s>0;s>>=1){ if (c<s) red[c]+=red[c+s]; __syncthreads(); }
        if (c==0) nrm[k] = fmaxf(sqrtf(red[0]), 1e-12f);
        __syncthreads();
    }
#pragma unroll
    for (int k=0;k<KK;k++) { vi[k] = vi[k]/nrm[k]; lds_ui[c][k] = vi[k]; ws[OFF_UINIT + c*KK + k] = vi[k]; }
    __syncthreads();
    float w0[KK];
#pragma unroll
    for (int k=0;k<KK;k++) w0[k] = (cnts[k]==0.f) ? pd[c*KK+k] : vi[k];
    for (int k=0;k<KK;k++) {
        red[c] = w0[k]*w0[k];
        __syncthreads();
        for (int s=128;s>0;s>>=1){ if (c<s) red[c]+=red[c+s]; __syncthreads(); }
        if (c==0) nrm[k] = fmaxf(sqrtf(red[0]), 1e-12f);
        __syncthreads();
    }
    unsigned short* ubf = (unsigned short*)(ws + OFF_UBF);
#pragma unroll
    for (int k=0;k<KK;k++) {
        float uv = w0[k] / nrm[k];
        ws[OFF_U + k*CC + c] = uv;
        ubf[k*264 + c] = f2bf(uv);
    }
    float m[KK]; float Kn=0.f;
#pragma unroll
    for (int k=0;k<KK;k++){ m[k] = (cnts[k]==0.f)?0.f:1.f; Kn += m[k]; }
    float csum = 0.f;
    for (int idx = c; idx < KK*KK; idx += 256) {
        int k1 = idx / KK, k2 = idx % KK;
        if (m[k1]!=0.f && m[k2]!=0.f) {
            float gg=0.f;
            for (int cc2=0; cc2<CC; cc2++) gg += lds_ui[cc2][k1]*lds_ui[cc2][k2];
            csum += gg;
        }
    }
    red[c]=csum; __syncthreads();
    for (int s=128;s>0;s>>=1){ if (c<s) red[c]+=red[c+s]; __syncthreads(); }
    if (c==0) ws[OFF_SCAL+4] = (red[0] - Kn) / (Kn * (Kn - 1.f));
}

// ---------------- PU via MFMA: 512 blocks = 2 bgrps (4 b each) x 256 pxtiles ----------------
__global__ __launch_bounds__(256) void pu_kernel(const unsigned short* __restrict__ featn,
                                                 const unsigned short* __restrict__ featn_T,
                                                 const unsigned short* __restrict__ ubf,
                                                 const float* __restrict__ aRbase,
                                                 float* __restrict__ aWbase,
                                                 float* __restrict__ upart,
                                                 int uniform_a) {
    __shared__ __attribute__((aligned(16))) unsigned short u_lds[32*264];
    __shared__ __attribute__((aligned(16))) unsigned short p_lds[32*72];
    int tid = threadIdx.x;
    {
        const uint4* src = (const uint4*)ubf;
        uint4* dst = (uint4*)u_lds;
        for (int i=tid; i<1056; i+=256) dst[i] = src[i];
    }
    __syncthreads();
    int blk = blockIdx.x;
    int pxtile = blk & 255;
    int bgrp = blk >> 8;          // 0..1
    int lane = tid & 63, wid = tid >> 6;
    int g = lane >> 4, lc = lane & 15;
    int px_w = pxtile*64 + wid*16;

    float a0r[4], a1r[4];
    if (uniform_a) {
#pragma unroll
        for (int r=0;r<4;r++){ a0r[r]=1.0f/(float)KK; a1r[r]=1.0f/(float)KK; }
    } else {
        int k1 = (lc+16 > KK-1) ? (KK-1) : (lc+16);
#pragma unroll
        for (int r=0;r<4;r++) {
            int pxg = px_w + g*4 + r;
            float s0 = aRbase[0*AQ + (size_t)pxg*32 + lc] + aRbase[1*AQ + (size_t)pxg*32 + lc];
            float s1 = aRbase[0*AQ + (size_t)pxg*32 + k1] + aRbase[1*AQ + (size_t)pxg*32 + k1];
            a0r[r] = s0*0.125f;
            a1r[r] = s1*0.125f;
        }
    }

    f32x4 upacc[4][2];
#pragma unroll
    for (int m=0;m<4;m++)
#pragma unroll
        for (int n=0;n<2;n++) upacc[m][n] = (f32x4){0.f,0.f,0.f,0.f};
    float aacc[2][4];
#pragma unroll
    for (int n=0;n<2;n++)
#pragma unroll
        for (int r=0;r<4;r++) aacc[n][r]=0.f;

    for (int bi=0; bi<4; bi++) {
        int bb = bgrp*4 + bi;
        const unsigned short* fb = featn + (size_t)bb*CC*PP;
        const unsigned short* fTrow = featn_T + ((size_t)bb*PP + px_w + lc)*CC;
        f32x4 acc0 = (f32x4){0.f,0.f,0.f,0.f};
        f32x4 acc1 = (f32x4){0.f,0.f,0.f,0.f};
#pragma unroll
        for (int ks=0; ks<8; ks++) {
            int cbase = ks*32 + g*8;
            union { uint4 u4; short8v s; } af, bf0, bf1;
            af.u4  = *(const uint4*)&fTrow[cbase];
            bf0.u4 = *(const uint4*)&u_lds[(size_t)lc*264 + cbase];
            bf1.u4 = *(const uint4*)&u_lds[(size_t)(lc+16)*264 + cbase];
            acc0 = __builtin_amdgcn_mfma_f32_16x16x32_bf16(af.s, bf0.s, acc0, 0,0,0);
            acc1 = __builtin_amdgcn_mfma_f32_16x16x32_bf16(af.s, bf1.s, acc1, 0,0,0);
        }
#pragma unroll
        for (int r=0;r<4;r++) {
            float e0 = a0r[r] * __expf(KA_C * acc0[r]);
            float e1 = (lc+16 < KK) ? a1r[r] * __expf(KA_C * acc1[r]) : 0.f;
            float sv = rowsum16(e0 + e1);
            float inv = 1.0f/sv;
            float p0 = e0*inv, p1 = e1*inv;
            aacc[0][r] += p0; aacc[1][r] += p1;
            int pl = wid*16 + g*4 + r;
            p_lds[(size_t)lc*72 + pl]      = f2bf(p0);
            p_lds[(size_t)(lc+16)*72 + pl] = f2bf(p1);
        }
        __syncthreads();
#pragma unroll
        for (int m=0;m<4;m++) {
            int c = wid*64 + m*16 + lc;
            const unsigned short* fr = fb + (size_t)c*PP + pxtile*64;
#pragma unroll
            for (int ks=0; ks<2; ks++) {
                int pxo = ks*32 + g*8;
                union { uint4 u4; short8v s; } af2, bp0, bp1;
                af2.u4 = *(const uint4*)&fr[pxo];
                bp0.u4 = *(const uint4*)&p_lds[(size_t)lc*72 + pxo];
                bp1.u4 = *(const uint4*)&p_lds[(size_t)(lc+16)*72 + pxo];
                upacc[m][0] = __builtin_amdgcn_mfma_f32_16x16x32_bf16(af2.s, bp0.s, upacc[m][0], 0,0,0);
                upacc[m][1] = __builtin_amdgcn_mfma_f32_16x16x32_bf16(af2.s, bp1.s, upacc[m][1], 0,0,0);
            }
        }
        __syncthreads();
    }
#pragma unroll
    for (int m=0;m<4;m++) {
        int cb = wid*64 + m*16 + g*4;
#pragma unroll
        for (int n=0;n<2;n++) {
            int kk = lc + 16*n;
            if (kk < KK) {
#pragma unroll
                for (int r=0;r<4;r++)
                    upart[(size_t)blk*4864 + (size_t)(cb+r)*KK + kk] = upacc[m][n][r];
            }
        }
    }
    float* aOut = aWbase + (size_t)bgrp*AQ;
#pragma unroll
    for (int n=0;n<2;n++) {
        int kk = lc + 16*n;
        if (kk < KK) {
#pragma unroll
            for (int r=0;r<4;r++) {
                int pxg = px_w + g*4 + r;
                aOut[(size_t)pxg*32 + kk] = aacc[n][r];
            }
        }
    }
}

// ---------------- R1: coalesced partial reduce (64 partials per chunk) ----------------
__global__ __launch_bounds__(256) void r1_kernel(const float* __restrict__ upart,
                                                 float* __restrict__ r1buf) {
    int blk = blockIdx.x;              // 152 = 8 ichunks * 19 echunks
    int echunk = blk % 19;
    int ichunk = blk / 19;
    int e = echunk*256 + threadIdx.x;
    float s = 0.f;
    int i0 = ichunk*64;
    for (int i=i0; i<i0+64; i++) s += upart[(size_t)i*4864 + e];
    r1buf[(size_t)ichunk*4864 + e] = s;
}

// ---------------- R2: 8-way sum + normalize -> u (f32 + bf16) ----------------
__global__ __launch_bounds__(256) void r2_kernel(const float* __restrict__ r1buf,
                                                 float* __restrict__ ws) {
    int k = blockIdx.x;   // 0..18
    int c = threadIdx.x;  // 0..255
    float s = 0.f;
#pragma unroll
    for (int i=0;i<8;i++) s += r1buf[(size_t)i*4864 + c*KK + k];
    __shared__ float red[256];
    red[c] = s*s; __syncthreads();
    for (int q=128;q>0;q>>=1){ if (c<q) red[c]+=red[c+q]; __syncthreads(); }
    float nrm = fmaxf(sqrtf(red[0]), 1e-12f);
    float uv = s / nrm;
    ws[OFF_U + k*CC + c] = uv;
    ((unsigned short*)(ws + OFF_UBF))[k*264 + c] = f2bf(uv);
}

// ---------------- protored2: 8-way sum -> proto ----------------
__global__ __launch_bounds__(256) void protored2_kernel(const float* __restrict__ r1buf,
                                                        float* __restrict__ ws) {
    int e = blockIdx.x*256 + threadIdx.x;   // 19*256 = 4864
    float s = 0.f;
#pragma unroll
    for (int i=0;i<8;i++) s += r1buf[(size_t)i*4864 + e];
    ws[OFF_PROTO + e] = s;
}

// ---------------- final via MFMA (coalesced logit_T + line-local a) ----------------
__global__ __launch_bounds__(256) void final_mfma_kernel(const unsigned short* __restrict__ featn_T,
                                                         const float* __restrict__ logt,
                                                         const int* __restrict__ target,
                                                         const unsigned short* __restrict__ ubf,
                                                         const float* __restrict__ aFbase,
                                                         float* __restrict__ scal) {
    __shared__ __attribute__((aligned(16))) unsigned short u_lds[32*264];
    int tid = threadIdx.x;
    {
        const uint4* src = (const uint4*)ubf;
        uint4* dst = (uint4*)u_lds;
        for (int i=tid; i<1056; i+=256) dst[i] = src[i];
    }
    __syncthreads();
    int blk = blockIdx.x;      // 512 = 2 bgrps x 256 pxtiles
    int pxtile = blk & 255;
    int bgrp = blk >> 8;
    int lane = tid & 63, wid = tid >> 6;
    int g = lane >> 4, lc = lane & 15;
    int px_w = pxtile*64 + wid*16;
    bool valid1 = (lc+16) < KK;

    float v_vmf=0.f, v_cons=0.f, v_ce=0.f, v_cnt=0.f;

    for (int bi=0; bi<4; bi++) {
        int bb = bgrp*4 + bi;
        const unsigned short* fTrow = featn_T + ((size_t)bb*PP + px_w + lc)*CC;
        f32x4 acc0 = (f32x4){0.f,0.f,0.f,0.f};
        f32x4 acc1 = (f32x4){0.f,0.f,0.f,0.f};
#pragma unroll
        for (int ks=0; ks<8; ks++) {
            int cbase = ks*32 + g*8;
            union { uint4 u4; short8v s; } af, bf0, bf1;
            af.u4  = *(const uint4*)&fTrow[cbase];
            bf0.u4 = *(const uint4*)&u_lds[(size_t)lc*264 + cbase];
            bf1.u4 = *(const uint4*)&u_lds[(size_t)(lc+16)*264 + cbase];
            acc0 = __builtin_amdgcn_mfma_f32_16x16x32_bf16(af.s, bf0.s, acc0, 0,0,0);
            acc1 = __builtin_amdgcn_mfma_f32_16x16x32_bf16(af.s, bf1.s, acc1, 0,0,0);
        }
#pragma unroll
        for (int r=0;r<4;r++) {
            int pxg = px_w + g*4 + r;
            float d0 = acc0[r], d1 = acc1[r];
            float av0 = (aFbase[0*AQ + (size_t)pxg*32 + lc] + aFbase[1*AQ + (size_t)pxg*32 + lc])*0.125f;
            float av1 = 0.f;
            if (valid1) {
                int k1 = lc+16;
                av1 = (aFbase[0*AQ + (size_t)pxg*32 + k1] + aFbase[1*AQ + (size_t)pxg*32 + k1])*0.125f;
            }
            float e0 = av0 * __expf(KA_C * d0);
            float e1 = valid1 ? av1 * __expf(KA_C * d1) : 0.f;
            float den = rowsum16(e0 + e1);
            float inv = 1.0f/den;
            float p0 = e0*inv, p1 = e1*inv;
            float vt = -p0*(__logf(av0+1e-6f) + KA_C*d0);
            if (valid1) vt += -p1*(__logf(av1+1e-6f) + KA_C*d1);
            float vt_row = rowsum16(vt);
            const float* lrow = logt + ((size_t)bb*PP + pxg)*20;
            float lg0 = lrow[lc];
            float lg1 = valid1 ? lrow[lc+16] : -3.4e38f;
            float mx = rowmax16(fmaxf(lg0, lg1));
            float sme = __expf(lg0-mx) + (valid1 ? __expf(lg1-mx) : 0.f);
            sme = rowsum16(sme);
            float lse = mx + __logf(sme);
            float ct = -p0*(lg0-lse);
            if (valid1) ct += -p1*(lg1-lse);
            float ct_row = rowsum16(ct);
            int t = target[(size_t)bb*PP + pxg];
            float ltt = (lc==t ? lg0 : 0.f) + ((valid1 && lc+16==t) ? lg1 : 0.f);
            float lt = rowsum16(ltt);
            if (lc==0) {
                v_vmf += vt_row;
                v_cons += ct_row;
                if (t != IGNORE_L) { v_ce += fmaxf(lse - lt, CETHR); v_cnt += 1.f; }
            }
        }
    }
    __shared__ float red[4][4];
    int w = tid >> 6;
    float v0=v_vmf, v1=v_cons, v2=v_ce, v3=v_cnt;
#pragma unroll
    for (int s=32;s>0;s>>=1) {
        v0 += __shfl_xor(v0, s); v1 += __shfl_xor(v1, s);
        v2 += __shfl_xor(v2, s); v3 += __shfl_xor(v3, s);
    }
    if ((tid&63)==0){ red[w][0]=v0; red[w][1]=v1; red[w][2]=v2; red[w][3]=v3; }
    __syncthreads();
    if (tid==0) {
        atomicAdd(&scal[0], red[0][0]+red[1][0]+red[2][0]+red[3][0]);
        atomicAdd(&scal[1], red[0][1]+red[1][1]+red[2][1]+red[3][1]);
        atomicAdd(&scal[2], red[0][2]+red[1][2]+red[2][2]+red[3][2]);
        atomicAdd(&scal[3], red[0][3]+red[1][3]+red[2][3]+red[3][3]);
    }
}

// ---------------- finalize ----------------
__global__ __launch_bounds__(256) void finalize_kernel(const float* __restrict__ ws,
                                                       float* __restrict__ out) {
    if (blockIdx.x==0 && threadIdx.x==0) {
        float cnt_all = (float)BB*(float)PP*(float)KK;
        float vmf  = ws[OFF_SCAL+0] / cnt_all / logf((float)KK);
        float cons = ws[OFF_SCAL+1] / cnt_all;
        float ce   = ws[OFF_SCAL+2] / (ws[OFF_SCAL+3] + 1e-6f);
        float contrast = ws[OFF_SCAL+4];
        out[0] = ce + vmf + contrast + cons;
    }
    int i = blockIdx.x*256 + threadIdx.x;
    if (i < 4864) out[1+i] = ws[OFF_PROTO+i];
    if (blockIdx.x==0 && threadIdx.x < KK) out[1+4864+threadIdx.x] = ws[OFF_COUNTS+threadIdx.x];
}

extern "C" void kernel_launch(void* const* d_in, const int* in_sizes, int n_in,
                              void* d_out, int out_size, void* d_ws, size_t ws_size,
                              hipStream_t stream) {
    (void)in_sizes; (void)n_in; (void)out_size; (void)ws_size;
    const float* logit  = (const float*)d_in[0];
    const int*   target = (const int*)d_in[1];
    const float* feat   = (const float*)d_in[2];
    const float* pd     = (const float*)d_in[4];
    float* out = (float*)d_out;
    float* ws  = (float*)d_ws;

    unsigned short* featn   = (unsigned short*)ws;
    unsigned short* featn_T = (unsigned short*)(ws + OFF_FEATNT);
    unsigned short* ubf     = (unsigned short*)(ws + OFF_UBF);
    float* upart = ws + OFF_UPART;
    float* r1buf = ws + OFF_R1;
    float* normf = ws + OFF_NORM;
    float* logt  = ws + OFF_LOGT;
    float* scal  = ws + OFF_SCAL;
    float* aSet[2] = { ws + OFF_A, ws + OFF_A + (size_t)2*AQ };

    hipMemsetAsync(ws + OFF_PROTO, 0, 4912*sizeof(float), stream);
    hipMemsetAsync(ws + OFF_UBF, 0, 4224*sizeof(float), stream);
    ssct_kernel<<<2048, 256, 0, stream>>>(feat, featn, featn_T, normf);
    counts_kernel<<<256, 256, 0, stream>>>(target, ws);
    logt_kernel<<<512, 256, 0, stream>>>(logit, logt);
    proto_mfma_kernel<<<512, 256, 0, stream>>>(featn, target, normf, upart);
    r1_kernel<<<152, 256, 0, stream>>>(upart, r1buf);
    protored2_kernel<<<19, 256, 0, stream>>>(r1buf, ws);
    setup_kernel<<<1, 256, 0, stream>>>(pd, ws);

    for (int t=0; t<10; t++) {
        if (t > 0) {
            r1_kernel<<<152, 256, 0, stream>>>(upart, r1buf);
            r2_kernel<<<KK, 256, 0, stream>>>(r1buf, ws);
        }
        pu_kernel<<<512, 256, 0, stream>>>(featn, featn_T, ubf,
                                           aSet[t&1], aSet[(t+1)&1],
                                           upart, (t==0)?1:0);
    }
    r1_kernel<<<152, 256, 0, stream>>>(upart, r1buf);
    r2_kernel<<<KK, 256, 0, stream>>>(r1buf, ws);
    final_mfma_kernel<<<512, 256, 0, stream>>>(featn_T, logt, target, ubf, aSet[0], scal);
    finalize_kernel<<<20, 256, 0, stream>>>(ws, out);
}